// Round 10
// baseline (331.306 us; speedup 1.0000x reference)
//
#include <hip/hip_runtime.h>
#include <hip/hip_bf16.h>

#define BN     6
#define NQ     10000
#define DIM    256
#define HEADS  8
#define HDD    32
#define HF_    32
#define WF_    88
#define HW_    (HF_*WF_)     /* 2816 */
#define MTOT   (BN*NQ)       /* 60000 */

typedef __attribute__((ext_vector_type(8))) unsigned short ushort8_t;
typedef __attribute__((ext_vector_type(8))) short bf16x8;
typedef __attribute__((ext_vector_type(4))) float f32x4;

static __device__ inline unsigned short f2bf(float x) {
    __hip_bfloat16 b = __float2bfloat16(x);
    return *(unsigned short*)&b;
}

// ---------------------------------------------------------------------------
// K_prep: merged weight-convert (blocks 0..63), ebias (64..87, 4x parallel),
// mask (88..127).
// ---------------------------------------------------------------------------
__global__ __launch_bounds__(256)
void k_prep(const float* __restrict__ Wv, const float* __restrict__ Wo,
            const float* __restrict__ Wa, const float* __restrict__ Wi,
            const float* __restrict__ Wz,
            const float* __restrict__ lvl, const float* __restrict__ cam,
            const float* __restrict__ bv, const int* __restrict__ bev,
            unsigned short* __restrict__ Wv_bf, unsigned short* __restrict__ Woa_bf,
            unsigned short* __restrict__ Wi_bf, unsigned short* __restrict__ Wz_bf,
            float* __restrict__ ebias, float* __restrict__ hitf,
            float* __restrict__ scale, float* __restrict__ biasf)
{
    const int b = blockIdx.x;
    const int tid = threadIdx.x;
    if (b < 64) {
        const int i4 = (b*256 + tid) * 4;
        if (i4 < 65536) {
            float4 v;
            ushort4 p;
            v = *(const float4*)(Wv+i4); p.x=f2bf(v.x);p.y=f2bf(v.y);p.z=f2bf(v.z);p.w=f2bf(v.w);
            *(ushort4*)(Wv_bf+i4) = p;
            v = *(const float4*)(Wi+i4); p.x=f2bf(v.x);p.y=f2bf(v.y);p.z=f2bf(v.z);p.w=f2bf(v.w);
            *(ushort4*)(Wi_bf+i4) = p;
            v = *(const float4*)(Wz+i4); p.x=f2bf(v.x);p.y=f2bf(v.y);p.z=f2bf(v.z);p.w=f2bf(v.w);
            *(ushort4*)(Wz_bf+i4) = p;
        }
        if (i4 < 32768) {
            float4 v = *(const float4*)(Wo+i4);
            ushort4 p; p.x=f2bf(v.x);p.y=f2bf(v.y);p.z=f2bf(v.z);p.w=f2bf(v.w);
            *(ushort4*)(Woa_bf+i4) = p;
        }
        if (i4 < 16384) {
            float4 v = *(const float4*)(Wa+i4);
            ushort4 p; p.x=f2bf(v.x);p.y=f2bf(v.y);p.z=f2bf(v.z);p.w=f2bf(v.w);
            *(ushort4*)(Woa_bf+32768+i4) = p;
        }
    } else if (b < 88) {
        // ebias: 24 blocks = (n, j-quad).  thread = (j within quad, d-quarter)
        const int idx = b - 64;
        const int n  = idx >> 2;
        const int jq = idx & 3;
        __shared__ float e[DIM];
        __shared__ float red[64][5];
        e[tid] = lvl[tid] + cam[n*DIM + tid];
        __syncthreads();
        const int j  = jq*64 + (tid >> 2);
        const int dq = tid & 3;
        const float* w  = Wv + (size_t)j*DIM + dq*64;
        const float* ee = e + dq*64;
        float s = 0.f;
        #pragma unroll
        for (int i = 0; i < 64; ++i) s += ee[i]*w[i];
        red[tid>>2][dq] = s;
        __syncthreads();
        if (dq == 0)
            ebias[n*DIM + j] = bv[j] + red[tid>>2][0] + red[tid>>2][1]
                                     + red[tid>>2][2] + red[tid>>2][3];
    } else {
        const int q = (b - 88)*256 + tid;
        if (q >= NQ) return;
        float cnt = 0.f;
        #pragma unroll
        for (int n = 0; n < BN; ++n) {
            int hit = 0;
            #pragma unroll
            for (int z = 0; z < 4; ++z)
                hit |= (bev[(((size_t)n*NQ + q)*4 + z)*2] != 0);
            hitf[(size_t)n*NQ + q] = (float)hit;
            cnt += (float)hit;
        }
        biasf[q] = (cnt > 0.f) ? 1.f : 0.f;
        scale[q] = 1.f / fmaxf(cnt, 1.f);
    }
}

// ---------------------------------------------------------------------------
// K_feat: transpose feat[cam][256 d][2816 p] f32 -> featT[cam][p][d] bf16.
// 64x64 tiles through LDS.
// ---------------------------------------------------------------------------
__global__ __launch_bounds__(256)
void k_feat(const float* __restrict__ feat, unsigned short* __restrict__ featT)
{
    __shared__ float Tf[64][68];
    const int cam = blockIdx.z;
    const int d0 = blockIdx.y * 64;
    const int p0 = blockIdx.x * 64;
    const int tid = threadIdx.x;
    #pragma unroll
    for (int i = 0; i < 4; ++i) {
        const int d = (tid>>4) + i*16;
        const int p4 = (tid&15)*4;
        *(float4*)&Tf[d][p4] = *(const float4*)(feat + ((size_t)cam*DIM + d0 + d)*HW_ + p0 + p4);
    }
    __syncthreads();
    const int p = tid>>2, dq = tid&3;
    unsigned short* ob = featT + ((size_t)cam*HW_ + p0 + p)*DIM + d0;
    #pragma unroll
    for (int i = 0; i < 4; ++i) {
        const int d4 = dq*4 + i*16;
        ushort4 pk;
        pk.x = f2bf(Tf[d4+0][p]); pk.y = f2bf(Tf[d4+1][p]);
        pk.z = f2bf(Tf[d4+2][p]); pk.w = f2bf(Tf[d4+3][p]);
        *(ushort4*)(ob + d4) = pk;
    }
}

// ---------------------------------------------------------------------------
// K1: value GEMM, r2-style barrier-free.  16 p-rows per block (1056 blocks);
// wave w owns 64 cols.  A frags per-lane 16B direct from bf16 featT; B frags
// per-lane from L2-resident Wv_bf.  Zero LDS in K-loop.  Epilogue: +ebias,
// bf16 -> C_lds[16][264], then 16B-granular segment stores into the
// [cam][h][p][32ch] value layout (replaces 8192 scalar 2B stores/block).
// ---------------------------------------------------------------------------
__global__ __launch_bounds__(256)
void k_value_mfma(const unsigned short* __restrict__ featT,
                  const unsigned short* __restrict__ Wv_bf,
                  const float* __restrict__ ebias,
                  unsigned short* __restrict__ value_bf)
{
    __shared__ unsigned short C_lds[16][264];
    const int cam = blockIdx.z;
    const int p0 = blockIdx.x * 16;
    const int tid = threadIdx.x;
    const int lane = tid & 63, wave = tid >> 6;
    const int quad = lane >> 4, l15 = lane & 15;
    const int n0 = wave * 64;

    const unsigned short* abase = featT + ((size_t)cam*HW_ + p0 + l15)*DIM;
    f32x4 acc[4] = {};

    #pragma unroll
    for (int kc = 0; kc < 8; ++kc) {
        const int kk = kc*32 + quad*8;
        const bf16x8 a = *(const bf16x8*)(abase + kk);
        #pragma unroll
        for (int nt = 0; nt < 4; ++nt) {
            const bf16x8 bfr = *(const bf16x8*)(Wv_bf + (size_t)(n0 + nt*16 + l15)*DIM + kk);
            acc[nt] = __builtin_amdgcn_mfma_f32_16x16x32_bf16(a, bfr, acc[nt], 0,0,0);
        }
    }

    #pragma unroll
    for (int nt = 0; nt < 4; ++nt) {
        const int col = n0 + nt*16 + l15;
        const float eb = ebias[cam*DIM + col];
        #pragma unroll
        for (int r = 0; r < 4; ++r)
            C_lds[quad*4 + r][col] = f2bf(acc[nt][r] + eb);
    }
    __syncthreads();
    // stores: 16 p x 8 h x 4 sixteens = 512 slots, 2/thread
    #pragma unroll
    for (int i = 0; i < 2; ++i) {
        const int idx = i*256 + tid;
        const int p = idx >> 5;
        const int seg = idx & 31;
        const int h = seg >> 2, part = seg & 3;
        unsigned short* dst = value_bf +
            ((size_t)(cam*HEADS + h)*HW_ + p0 + p)*HDD + part*8;
        *(ushort8_t*)dst = *(const ushort8_t*)&C_lds[p][h*32 + part*8];
    }
}

// ---------------------------------------------------------------------------
// K2a: off/attn GEMM with fused Qr+Pe add/convert, B reg-prefetch, LDS
// epilogue with contiguous stores, and softmax applied in the epilogue
// (attw_ws stores PROBABILITIES).  FROZEN (best-known).
// ---------------------------------------------------------------------------
__global__ __launch_bounds__(256, 3)
void k_offattn(const float* __restrict__ Qr, const float* __restrict__ Pe,
               const unsigned short* __restrict__ Woa_bf,
               const float* __restrict__ boff, const float* __restrict__ battn,
               float* __restrict__ off_ws, float* __restrict__ attw_ws)
{
    __shared__ char smraw[32*204*4];
    unsigned short (*A_lds)[264] = (unsigned short (*)[264])smraw;
    float (*C_lds)[204] = (float (*)[204])smraw;

    const int m0 = blockIdx.x * 32;
    const int tid = threadIdx.x;
    const int lane = tid & 63, wave = tid >> 6;
    const int quad = lane >> 4, l15 = lane & 15;
    const int n0 = wave * 48;

    // --- B prefetch: all 24 fragments, issued before the stage barrier ---
    bf16x8 breg[3][8];
    #pragma unroll
    for (int nt = 0; nt < 3; ++nt) {
        const unsigned short* wb = Woa_bf + (size_t)(n0 + nt*16 + l15)*DIM + quad*8;
        #pragma unroll
        for (int kc = 0; kc < 8; ++kc)
            breg[nt][kc] = *(const bf16x8*)(wb + kc*32);
    }

    // --- A stage: coalesced f32 loads, add, cvt -> LDS ---
    {
        const int row = tid >> 3;       // 0..31
        const int c8  = tid & 7;
        const float* qb = Qr + (size_t)(m0 + row)*DIM;
        const float* pb = Pe + (size_t)(m0 + row)*DIM;
        #pragma unroll
        for (int j = 0; j < 8; ++j) {
            const int col = c8*4 + j*32;
            const float4 x = *(const float4*)(qb + col);
            const float4 y = *(const float4*)(pb + col);
            ushort4 pk;
            pk.x = f2bf(x.x+y.x); pk.y = f2bf(x.y+y.y);
            pk.z = f2bf(x.z+y.z); pk.w = f2bf(x.w+y.w);
            *(ushort4*)&A_lds[row][col] = pk;
        }
    }
    __syncthreads();

    // --- K loop: LDS reads + MFMA only ---
    f32x4 acc[2][3] = {};
    #pragma unroll
    for (int kc = 0; kc < 8; ++kc) {
        const int kk = kc*32 + quad*8;
        const bf16x8 a0 = *(const bf16x8*)&A_lds[l15][kk];
        const bf16x8 a1 = *(const bf16x8*)&A_lds[16 + l15][kk];
        #pragma unroll
        for (int nt = 0; nt < 3; ++nt) {
            acc[0][nt] = __builtin_amdgcn_mfma_f32_16x16x32_bf16(a0, breg[nt][kc], acc[0][nt], 0,0,0);
            acc[1][nt] = __builtin_amdgcn_mfma_f32_16x16x32_bf16(a1, breg[nt][kc], acc[1][nt], 0,0,0);
        }
    }

    // --- epilogue: acc(+bias) -> LDS, softmax on attn cols, contiguous stores
    __syncthreads();   // all A_lds reads done before overwrite
    #pragma unroll
    for (int nt = 0; nt < 3; ++nt) {
        const int col = n0 + nt*16 + l15;
        const float bias = (col < 128) ? boff[col] : battn[col-128];
        #pragma unroll
        for (int mt = 0; mt < 2; ++mt) {
            #pragma unroll
            for (int r = 0; r < 4; ++r)
                C_lds[mt*16 + quad*4 + r][col] = acc[mt][nt][r] + bias;
        }
    }
    __syncthreads();
    // softmax: thread (row = tid>>3, h = tid&7) over 8 contiguous logits
    {
        float* a = &C_lds[tid>>3][128 + (tid&7)*8];
        float lg[8];
        float mx = -1e30f;
        #pragma unroll
        for (int p = 0; p < 8; ++p) { lg[p] = a[p]; mx = fmaxf(mx, lg[p]); }
        float ssum = 0.f;
        #pragma unroll
        for (int p = 0; p < 8; ++p) { lg[p] = __expf(lg[p]-mx); ssum += lg[p]; }
        const float inv = 1.f/ssum;
        #pragma unroll
        for (int p = 0; p < 8; ++p) a[p] = lg[p]*inv;
    }
    __syncthreads();
    // off: 32 rows x 128 f32 = 1024 float4, 4/thread, lane-contiguous
    #pragma unroll
    for (int i = 0; i < 4; ++i) {
        const int idx = i*256 + tid;
        const int row = idx >> 5, c4 = (idx & 31)*4;
        *(float4*)(off_ws + ((size_t)(m0+row))*128 + c4) = *(float4*)&C_lds[row][c4];
    }
    // attw (probabilities): 32 rows x 64 f32 = 512 float4, 2/thread
    #pragma unroll
    for (int i = 0; i < 2; ++i) {
        const int idx = i*256 + tid;
        const int row = idx >> 4, c4 = (idx & 15)*4;
        *(float4*)(attw_ws + ((size_t)(m0+row))*64 + c4) = *(float4*)&C_lds[row][128 + c4];
    }
}

// ---------------------------------------------------------------------------
// K2b: sampling fused with camera reduce.  FROZEN (best-known): quarter-split
// 256 thr, 8q/block, acc[8], VGPR~60.  attw_ws holds probabilities.
// ---------------------------------------------------------------------------
__global__ __launch_bounds__(256)
void k_sample(const unsigned short* __restrict__ value_bf,
              const float* __restrict__ off_ws, const float* __restrict__ attw_ws,
              const float* __restrict__ ref3d, const float* __restrict__ hitf,
              const float* __restrict__ scale, unsigned short* __restrict__ asum_bf)
{
    const int q0 = blockIdx.x * 8;
    const int tid = threadIdx.x;

    __shared__ float s_off[8][128];
    __shared__ float s_att[8][64];
    __shared__ float s_ref[8][8];
    __shared__ float s_hit[BN][8];
    __shared__ float s_scl[8];

    if (tid < 48) s_hit[tid>>3][tid&7] = hitf[(size_t)(tid>>3)*NQ + q0 + (tid&7)];
    if (tid < 8)  s_scl[tid] = scale[q0 + tid];

    const int quarter = tid & 3;
    const int h  = (tid >> 2) & 7;
    const int ql = tid >> 5;

    float acc[8];
    #pragma unroll
    for (int c = 0; c < 8; ++c) acc[c] = 0.f;

    for (int n = 0; n < BN; ++n) {
        __syncthreads();
        {
            const float4* so = (const float4*)(off_ws + ((size_t)n*NQ + q0)*128);
            ((float4*)&s_off[0][0])[tid] = so[tid];
            const float2* sa = (const float2*)(attw_ws + ((size_t)n*NQ + q0)*64);
            ((float2*)&s_att[0][0])[tid] = sa[tid];
            if (tid < 64)
                (&s_ref[0][0])[tid] = (ref3d + ((size_t)n*NQ + q0)*8)[tid];
        }
        __syncthreads();

        if (s_hit[n][ql] != 0.f) {
            const unsigned short* vbase =
                value_bf + (size_t)(n*HEADS + h)*HW_*HDD + quarter*8;

            #pragma unroll
            for (int p = 0; p < 8; ++p) {
                const int z = p & 3;
                const float wp = s_att[ql][h*8+p];   // precomputed probability
                const float ax = s_ref[ql][z*2+0]*WF_ + s_off[ql][h*16+p*2+0] - 0.5f;
                const float ay = s_ref[ql][z*2+1]*HF_ + s_off[ql][h*16+p*2+1] - 0.5f;
                const float fx = floorf(ax), fy = floorf(ay);
                const float dx = ax-fx, dy = ay-fy;
                const int x0 = (int)fx, y0 = (int)fy;
                #pragma unroll
                for (int oy = 0; oy < 2; ++oy) {
                    const int yi = y0 + oy;
                    const float wy = oy ? dy : 1.f-dy;
                    #pragma unroll
                    for (int ox = 0; ox < 2; ++ox) {
                        const int xi = x0 + ox;
                        const float wx = ox ? dx : 1.f-dx;
                        const bool valid = ((unsigned)xi < WF_) & ((unsigned)yi < HF_);
                        const float cw = valid ? wp*wy*wx : 0.f;
                        const int xc = min(max(xi, 0), WF_-1);
                        const int yc = min(max(yi, 0), HF_-1);
                        const ushort8_t v = *(const ushort8_t*)(vbase + (size_t)(yc*WF_ + xc)*HDD);
                        #pragma unroll
                        for (int c = 0; c < 8; ++c)
                            acc[c] += cw * __uint_as_float(((unsigned)v[c]) << 16);
                    }
                }
            }
        }
    }

    const float sc = s_scl[ql];
    ushort8_t o;
    #pragma unroll
    for (int c = 0; c < 8; ++c) o[c] = f2bf(acc[c]*sc);
    *(ushort8_t*)(asum_bf + ((size_t)(q0+ql))*DIM + h*HDD + quarter*8) = o;
}

// ---------------------------------------------------------------------------
// K_tail: FUSED inner+output projection (unchanged from r9).
// ---------------------------------------------------------------------------
__global__ __launch_bounds__(256)
void k_tail(const unsigned short* __restrict__ asum_bf,
            const unsigned short* __restrict__ Wi_bf,
            const unsigned short* __restrict__ Wz_bf,
            const float* __restrict__ bi, const float* __restrict__ bz,
            const float* __restrict__ biasf, float* __restrict__ out)
{
    __shared__ char smraw[32*260*4];   // union: S_lds bf16[32][264] / C_lds f32[32][260]
    unsigned short (*S_lds)[264] = (unsigned short (*)[264])smraw;
    float (*C_lds)[260] = (float (*)[260])smraw;

    const int m0 = blockIdx.x * 32;
    const int tid = threadIdx.x;
    const int lane = tid & 63, wave = tid >> 6;
    const int quad = lane >> 4, l15 = lane & 15;
    const int n0 = wave * 64;

    const int r0 = m0 + l15;
    const int r1 = m0 + 16 + l15;
    const unsigned short* a0p = asum_bf + (size_t)(r0 < NQ ? r0 : 0)*DIM;
    const unsigned short* a1p = asum_bf + (size_t)(r1 < NQ ? r1 : 0)*DIM;

    // --- phase 1: S = asum · Wi^T ---
    f32x4 acc[2][4] = {};
    #pragma unroll
    for (int kc = 0; kc < 8; ++kc) {
        const int kk = kc*32 + quad*8;
        const bf16x8 a0 = *(const bf16x8*)(a0p + kk);
        const bf16x8 a1 = *(const bf16x8*)(a1p + kk);
        #pragma unroll
        for (int nt = 0; nt < 4; ++nt) {
            const bf16x8 b = *(const bf16x8*)(Wi_bf + (size_t)(n0 + nt*16 + l15)*DIM + kk);
            acc[0][nt] = __builtin_amdgcn_mfma_f32_16x16x32_bf16(a0, b, acc[0][nt], 0,0,0);
            acc[1][nt] = __builtin_amdgcn_mfma_f32_16x16x32_bf16(a1, b, acc[1][nt], 0,0,0);
        }
    }
    #pragma unroll
    for (int nt = 0; nt < 4; ++nt) {
        const int col = n0 + nt*16 + l15;
        const float bj = bi[col];
        #pragma unroll
        for (int mt = 0; mt < 2; ++mt) {
            #pragma unroll
            for (int r = 0; r < 4; ++r) {
                const int m = m0 + mt*16 + quad*4 + r;
                const float f = (m < NQ) ? biasf[m] : 0.f;
                S_lds[mt*16 + quad*4 + r][col] = f2bf(acc[mt][nt][r] + f*bj);
            }
        }
    }
    __syncthreads();

    // --- phase 2: out = S · Wz^T ---
    f32x4 acc2[2][4] = {};
    #pragma unroll
    for (int kc = 0; kc < 8; ++kc) {
        const int kk = kc*32 + quad*8;
        const bf16x8 s0 = *(const bf16x8*)&S_lds[l15][kk];
        const bf16x8 s1 = *(const bf16x8*)&S_lds[16 + l15][kk];
        #pragma unroll
        for (int nt = 0; nt < 4; ++nt) {
            const bf16x8 b = *(const bf16x8*)(Wz_bf + (size_t)(n0 + nt*16 + l15)*DIM + kk);
            acc2[0][nt] = __builtin_amdgcn_mfma_f32_16x16x32_bf16(s0, b, acc2[0][nt], 0,0,0);
            acc2[1][nt] = __builtin_amdgcn_mfma_f32_16x16x32_bf16(s1, b, acc2[1][nt], 0,0,0);
        }
    }
    __syncthreads();   // all S_lds reads done before C_lds overwrite
    #pragma unroll
    for (int nt = 0; nt < 4; ++nt) {
        const int col = n0 + nt*16 + l15;
        const float bj = bz[col];
        #pragma unroll
        for (int mt = 0; mt < 2; ++mt) {
            #pragma unroll
            for (int r = 0; r < 4; ++r)
                C_lds[mt*16 + quad*4 + r][col] = acc2[mt][nt][r] + bj;
        }
    }
    __syncthreads();
    // coalesced stores: 32 rows x 256 f32 = 2048 float4, 8/thread
    #pragma unroll
    for (int i = 0; i < 8; ++i) {
        const int idx = i*256 + tid;
        const int row = idx >> 6, c4 = (idx & 63)*4;
        const int m = m0 + row;
        if (m < NQ)
            *(float4*)(out + (size_t)m*DIM + c4) = *(float4*)&C_lds[row][c4];
    }
}

// ---------------------------------------------------------------------------
extern "C" void kernel_launch(void* const* d_in, const int* in_sizes, int n_in,
                              void* d_out, int out_size, void* d_ws, size_t ws_size,
                              hipStream_t stream)
{
    const float* queries = (const float*)d_in[0];
    const float* pos_emb = (const float*)d_in[1];
    const float* lvl_emb = (const float*)d_in[2];
    const float* cam_emb = (const float*)d_in[3];
    const float* features= (const float*)d_in[4];
    const float* ref3d   = (const float*)d_in[5];
    const int*   bev     = (const int*)d_in[6];
    const float* Wv = (const float*)d_in[7];
    const float* bv = (const float*)d_in[8];
    const float* Wo = (const float*)d_in[9];
    const float* bo = (const float*)d_in[10];
    const float* Wa = (const float*)d_in[11];
    const float* ba = (const float*)d_in[12];
    const float* Wi = (const float*)d_in[13];
    const float* bi = (const float*)d_in[14];
    const float* Wz = (const float*)d_in[15];
    const float* bz = (const float*)d_in[16];
    float* out = (float*)d_out;

    char* ws = (char*)d_ws;
    size_t o = 0;
    auto alloc = [&](size_t bytes) { char* p = ws + o; o += (bytes + 255) & ~size_t(255); return p; };
    unsigned short* value_bf = (unsigned short*)alloc((size_t)BN*HEADS*HW_*HDD*2);  // 8.65 MB
    unsigned short* featT    = (unsigned short*)alloc((size_t)BN*HW_*DIM*2);        // 8.65 MB
    float* off_ws   = (float*)alloc((size_t)MTOT*128*4);                            // 30.7 MB
    float* attw_ws  = (float*)alloc((size_t)MTOT*64*4);                             // 15.4 MB
    unsigned short* asum_bf  = (unsigned short*)alloc((size_t)NQ*DIM*2);            // 5.1 MB
    unsigned short* Wv_bf  = (unsigned short*)alloc(65536*2);
    unsigned short* Woa_bf = (unsigned short*)alloc(49152*2);
    unsigned short* Wi_bf  = (unsigned short*)alloc(65536*2);
    unsigned short* Wz_bf  = (unsigned short*)alloc(65536*2);
    float* hitf   = (float*)alloc((size_t)BN*NQ*4);
    float* scalev = (float*)alloc(NQ*4);
    float* biasf  = (float*)alloc(NQ*4);
    float* ebias  = (float*)alloc(BN*DIM*4);
    // total ~69 MB

    k_prep  <<<128, 256, 0, stream>>>(Wv, Wo, Wa, Wi, Wz, lvl_emb, cam_emb, bv, bev,
                                      Wv_bf, Woa_bf, Wi_bf, Wz_bf,
                                      ebias, hitf, scalev, biasf);
    k_feat  <<<dim3(HW_/64, DIM/64, BN), 256, 0, stream>>>(features, featT);
    k_value_mfma<<<dim3(HW_/16, 1, BN), 256, 0, stream>>>(featT, Wv_bf, ebias, value_bf);
    k_offattn<<<MTOT/32, 256, 0, stream>>>(queries, pos_emb, Woa_bf, bo, ba, off_ws, attw_ws);
    k_sample <<<NQ/8, 256, 0, stream>>>(value_bf, off_ws, attw_ws, ref3d, hitf, scalev, asum_bf);
    k_tail   <<<(NQ+31)/32, 256, 0, stream>>>(asum_bf, Wi_bf, Wz_bf, bi, bz, biasf, out);
}

// Round 11
// 326.642 us; speedup vs baseline: 1.0143x; 1.0143x over previous
//
#include <hip/hip_runtime.h>
#include <hip/hip_bf16.h>

#define BN     6
#define NQ     10000
#define DIM    256
#define HEADS  8
#define HDD    32
#define HF_    32
#define WF_    88
#define HW_    (HF_*WF_)     /* 2816 */
#define MTOT   (BN*NQ)       /* 60000 */

typedef __attribute__((ext_vector_type(8))) unsigned short ushort8_t;
typedef __attribute__((ext_vector_type(8))) short bf16x8;
typedef __attribute__((ext_vector_type(4))) float f32x4;

static __device__ inline unsigned short f2bf(float x) {
    __hip_bfloat16 b = __float2bfloat16(x);
    return *(unsigned short*)&b;
}

// ---------------------------------------------------------------------------
// K_prep: merged weight-convert (blocks 0..63), ebias (64..87, 4x parallel),
// mask (88..127).
// ---------------------------------------------------------------------------
__global__ __launch_bounds__(256)
void k_prep(const float* __restrict__ Wv, const float* __restrict__ Wo,
            const float* __restrict__ Wa, const float* __restrict__ Wi,
            const float* __restrict__ Wz,
            const float* __restrict__ lvl, const float* __restrict__ cam,
            const float* __restrict__ bv, const int* __restrict__ bev,
            unsigned short* __restrict__ Wv_bf, unsigned short* __restrict__ Woa_bf,
            unsigned short* __restrict__ Wi_bf, unsigned short* __restrict__ Wz_bf,
            float* __restrict__ ebias, float* __restrict__ hitf,
            float* __restrict__ scale, float* __restrict__ biasf)
{
    const int b = blockIdx.x;
    const int tid = threadIdx.x;
    if (b < 64) {
        const int i4 = (b*256 + tid) * 4;
        if (i4 < 65536) {
            float4 v;
            ushort4 p;
            v = *(const float4*)(Wv+i4); p.x=f2bf(v.x);p.y=f2bf(v.y);p.z=f2bf(v.z);p.w=f2bf(v.w);
            *(ushort4*)(Wv_bf+i4) = p;
            v = *(const float4*)(Wi+i4); p.x=f2bf(v.x);p.y=f2bf(v.y);p.z=f2bf(v.z);p.w=f2bf(v.w);
            *(ushort4*)(Wi_bf+i4) = p;
            v = *(const float4*)(Wz+i4); p.x=f2bf(v.x);p.y=f2bf(v.y);p.z=f2bf(v.z);p.w=f2bf(v.w);
            *(ushort4*)(Wz_bf+i4) = p;
        }
        if (i4 < 32768) {
            float4 v = *(const float4*)(Wo+i4);
            ushort4 p; p.x=f2bf(v.x);p.y=f2bf(v.y);p.z=f2bf(v.z);p.w=f2bf(v.w);
            *(ushort4*)(Woa_bf+i4) = p;
        }
        if (i4 < 16384) {
            float4 v = *(const float4*)(Wa+i4);
            ushort4 p; p.x=f2bf(v.x);p.y=f2bf(v.y);p.z=f2bf(v.z);p.w=f2bf(v.w);
            *(ushort4*)(Woa_bf+32768+i4) = p;
        }
    } else if (b < 88) {
        // ebias: 24 blocks = (n, j-quad).  thread = (j within quad, d-quarter)
        const int idx = b - 64;
        const int n  = idx >> 2;
        const int jq = idx & 3;
        __shared__ float e[DIM];
        __shared__ float red[64][5];
        e[tid] = lvl[tid] + cam[n*DIM + tid];
        __syncthreads();
        const int j  = jq*64 + (tid >> 2);
        const int dq = tid & 3;
        const float* w  = Wv + (size_t)j*DIM + dq*64;
        const float* ee = e + dq*64;
        float s = 0.f;
        #pragma unroll
        for (int i = 0; i < 64; ++i) s += ee[i]*w[i];
        red[tid>>2][dq] = s;
        __syncthreads();
        if (dq == 0)
            ebias[n*DIM + j] = bv[j] + red[tid>>2][0] + red[tid>>2][1]
                                     + red[tid>>2][2] + red[tid>>2][3];
    } else {
        const int q = (b - 88)*256 + tid;
        if (q >= NQ) return;
        float cnt = 0.f;
        #pragma unroll
        for (int n = 0; n < BN; ++n) {
            int hit = 0;
            #pragma unroll
            for (int z = 0; z < 4; ++z)
                hit |= (bev[(((size_t)n*NQ + q)*4 + z)*2] != 0);
            hitf[(size_t)n*NQ + q] = (float)hit;
            cnt += (float)hit;
        }
        biasf[q] = (cnt > 0.f) ? 1.f : 0.f;
        scale[q] = 1.f / fmaxf(cnt, 1.f);
    }
}

// ---------------------------------------------------------------------------
// K1: value GEMM with FUSED feature transpose (replaces k_feat + old k_value).
// Per block: 16 pixels x 64 cols, K=256.  Stage: load f32 feat tile
// [256 d][16 p] directly (float4 per 4-thread group, 64B segments), cvt ->
// A_lds[16][264] bf16 (transposed).  One barrier.  K-loop: A from LDS, B
// per-lane from L2-resident Wv_bf.  Epilogue: +ebias, bf16 -> C_lds, then
// 16B-granular segment stores into value layout.  Deletes the 17.3MB featT
// round-trip and one launch.
// ---------------------------------------------------------------------------
__global__ __launch_bounds__(256)
void k_value_mfma(const float* __restrict__ feat,
                  const unsigned short* __restrict__ Wv_bf,
                  const float* __restrict__ ebias,
                  unsigned short* __restrict__ value_bf)
{
    __shared__ unsigned short A_lds[16][264];
    __shared__ unsigned short C_lds[16][264];
    const int cam = blockIdx.z;
    const int p0 = blockIdx.x * 16;
    const int tid = threadIdx.x;
    const int lane = tid & 63, wave = tid >> 6;
    const int quad = lane >> 4, l15 = lane & 15;
    const int n0 = wave * 64;

    // --- stage + transpose: thread t -> d = (t>>2)+i*64, p = (t&3)*4..+3 ---
    {
        const int dbase = tid >> 2;
        const int pq = (tid & 3) * 4;
        #pragma unroll
        for (int i = 0; i < 4; ++i) {
            const int d = dbase + i*64;
            const float4 v = *(const float4*)(feat + ((size_t)cam*DIM + d)*HW_ + p0 + pq);
            A_lds[pq+0][d] = f2bf(v.x);
            A_lds[pq+1][d] = f2bf(v.y);
            A_lds[pq+2][d] = f2bf(v.z);
            A_lds[pq+3][d] = f2bf(v.w);
        }
    }
    __syncthreads();

    // --- K loop: A from LDS, B per-lane from L2-hot Wv_bf ---
    f32x4 acc[4] = {};
    #pragma unroll
    for (int kc = 0; kc < 8; ++kc) {
        const int kk = kc*32 + quad*8;
        const bf16x8 a = *(const bf16x8*)&A_lds[l15][kk];
        #pragma unroll
        for (int nt = 0; nt < 4; ++nt) {
            const bf16x8 bfr = *(const bf16x8*)(Wv_bf + (size_t)(n0 + nt*16 + l15)*DIM + kk);
            acc[nt] = __builtin_amdgcn_mfma_f32_16x16x32_bf16(a, bfr, acc[nt], 0,0,0);
        }
    }

    #pragma unroll
    for (int nt = 0; nt < 4; ++nt) {
        const int col = n0 + nt*16 + l15;
        const float eb = ebias[cam*DIM + col];
        #pragma unroll
        for (int r = 0; r < 4; ++r)
            C_lds[quad*4 + r][col] = f2bf(acc[nt][r] + eb);
    }
    __syncthreads();
    // stores: 16 p x 8 h x 4 sixteens = 512 slots, 2/thread
    #pragma unroll
    for (int i = 0; i < 2; ++i) {
        const int idx = i*256 + tid;
        const int p = idx >> 5;
        const int seg = idx & 31;
        const int h = seg >> 2, part = seg & 3;
        unsigned short* dst = value_bf +
            ((size_t)(cam*HEADS + h)*HW_ + p0 + p)*HDD + part*8;
        *(ushort8_t*)dst = *(const ushort8_t*)&C_lds[p][h*32 + part*8];
    }
}

// ---------------------------------------------------------------------------
// K2a: off/attn GEMM with fused Qr+Pe add/convert, B reg-prefetch, LDS
// epilogue with contiguous stores, and softmax applied in the epilogue
// (attw_ws stores PROBABILITIES).  FROZEN (best-known).
// ---------------------------------------------------------------------------
__global__ __launch_bounds__(256, 3)
void k_offattn(const float* __restrict__ Qr, const float* __restrict__ Pe,
               const unsigned short* __restrict__ Woa_bf,
               const float* __restrict__ boff, const float* __restrict__ battn,
               float* __restrict__ off_ws, float* __restrict__ attw_ws)
{
    __shared__ char smraw[32*204*4];
    unsigned short (*A_lds)[264] = (unsigned short (*)[264])smraw;
    float (*C_lds)[204] = (float (*)[204])smraw;

    const int m0 = blockIdx.x * 32;
    const int tid = threadIdx.x;
    const int lane = tid & 63, wave = tid >> 6;
    const int quad = lane >> 4, l15 = lane & 15;
    const int n0 = wave * 48;

    // --- B prefetch: all 24 fragments, issued before the stage barrier ---
    bf16x8 breg[3][8];
    #pragma unroll
    for (int nt = 0; nt < 3; ++nt) {
        const unsigned short* wb = Woa_bf + (size_t)(n0 + nt*16 + l15)*DIM + quad*8;
        #pragma unroll
        for (int kc = 0; kc < 8; ++kc)
            breg[nt][kc] = *(const bf16x8*)(wb + kc*32);
    }

    // --- A stage: coalesced f32 loads, add, cvt -> LDS ---
    {
        const int row = tid >> 3;       // 0..31
        const int c8  = tid & 7;
        const float* qb = Qr + (size_t)(m0 + row)*DIM;
        const float* pb = Pe + (size_t)(m0 + row)*DIM;
        #pragma unroll
        for (int j = 0; j < 8; ++j) {
            const int col = c8*4 + j*32;
            const float4 x = *(const float4*)(qb + col);
            const float4 y = *(const float4*)(pb + col);
            ushort4 pk;
            pk.x = f2bf(x.x+y.x); pk.y = f2bf(x.y+y.y);
            pk.z = f2bf(x.z+y.z); pk.w = f2bf(x.w+y.w);
            *(ushort4*)&A_lds[row][col] = pk;
        }
    }
    __syncthreads();

    // --- K loop: LDS reads + MFMA only ---
    f32x4 acc[2][3] = {};
    #pragma unroll
    for (int kc = 0; kc < 8; ++kc) {
        const int kk = kc*32 + quad*8;
        const bf16x8 a0 = *(const bf16x8*)&A_lds[l15][kk];
        const bf16x8 a1 = *(const bf16x8*)&A_lds[16 + l15][kk];
        #pragma unroll
        for (int nt = 0; nt < 3; ++nt) {
            acc[0][nt] = __builtin_amdgcn_mfma_f32_16x16x32_bf16(a0, breg[nt][kc], acc[0][nt], 0,0,0);
            acc[1][nt] = __builtin_amdgcn_mfma_f32_16x16x32_bf16(a1, breg[nt][kc], acc[1][nt], 0,0,0);
        }
    }

    // --- epilogue: acc(+bias) -> LDS, softmax on attn cols, contiguous stores
    __syncthreads();   // all A_lds reads done before overwrite
    #pragma unroll
    for (int nt = 0; nt < 3; ++nt) {
        const int col = n0 + nt*16 + l15;
        const float bias = (col < 128) ? boff[col] : battn[col-128];
        #pragma unroll
        for (int mt = 0; mt < 2; ++mt) {
            #pragma unroll
            for (int r = 0; r < 4; ++r)
                C_lds[mt*16 + quad*4 + r][col] = acc[mt][nt][r] + bias;
        }
    }
    __syncthreads();
    // softmax: thread (row = tid>>3, h = tid&7) over 8 contiguous logits
    {
        float* a = &C_lds[tid>>3][128 + (tid&7)*8];
        float lg[8];
        float mx = -1e30f;
        #pragma unroll
        for (int p = 0; p < 8; ++p) { lg[p] = a[p]; mx = fmaxf(mx, lg[p]); }
        float ssum = 0.f;
        #pragma unroll
        for (int p = 0; p < 8; ++p) { lg[p] = __expf(lg[p]-mx); ssum += lg[p]; }
        const float inv = 1.f/ssum;
        #pragma unroll
        for (int p = 0; p < 8; ++p) a[p] = lg[p]*inv;
    }
    __syncthreads();
    // off: 32 rows x 128 f32 = 1024 float4, 4/thread, lane-contiguous
    #pragma unroll
    for (int i = 0; i < 4; ++i) {
        const int idx = i*256 + tid;
        const int row = idx >> 5, c4 = (idx & 31)*4;
        *(float4*)(off_ws + ((size_t)(m0+row))*128 + c4) = *(float4*)&C_lds[row][c4];
    }
    // attw (probabilities): 32 rows x 64 f32 = 512 float4, 2/thread
    #pragma unroll
    for (int i = 0; i < 2; ++i) {
        const int idx = i*256 + tid;
        const int row = idx >> 4, c4 = (idx & 15)*4;
        *(float4*)(attw_ws + ((size_t)(m0+row))*64 + c4) = *(float4*)&C_lds[row][128 + c4];
    }
}

// ---------------------------------------------------------------------------
// K2b: sampling fused with camera reduce.  FROZEN (best-known): quarter-split
// 256 thr, 8q/block, acc[8], VGPR~60.  attw_ws holds probabilities.
// ---------------------------------------------------------------------------
__global__ __launch_bounds__(256)
void k_sample(const unsigned short* __restrict__ value_bf,
              const float* __restrict__ off_ws, const float* __restrict__ attw_ws,
              const float* __restrict__ ref3d, const float* __restrict__ hitf,
              const float* __restrict__ scale, unsigned short* __restrict__ asum_bf)
{
    const int q0 = blockIdx.x * 8;
    const int tid = threadIdx.x;

    __shared__ float s_off[8][128];
    __shared__ float s_att[8][64];
    __shared__ float s_ref[8][8];
    __shared__ float s_hit[BN][8];
    __shared__ float s_scl[8];

    if (tid < 48) s_hit[tid>>3][tid&7] = hitf[(size_t)(tid>>3)*NQ + q0 + (tid&7)];
    if (tid < 8)  s_scl[tid] = scale[q0 + tid];

    const int quarter = tid & 3;
    const int h  = (tid >> 2) & 7;
    const int ql = tid >> 5;

    float acc[8];
    #pragma unroll
    for (int c = 0; c < 8; ++c) acc[c] = 0.f;

    for (int n = 0; n < BN; ++n) {
        __syncthreads();
        {
            const float4* so = (const float4*)(off_ws + ((size_t)n*NQ + q0)*128);
            ((float4*)&s_off[0][0])[tid] = so[tid];
            const float2* sa = (const float2*)(attw_ws + ((size_t)n*NQ + q0)*64);
            ((float2*)&s_att[0][0])[tid] = sa[tid];
            if (tid < 64)
                (&s_ref[0][0])[tid] = (ref3d + ((size_t)n*NQ + q0)*8)[tid];
        }
        __syncthreads();

        if (s_hit[n][ql] != 0.f) {
            const unsigned short* vbase =
                value_bf + (size_t)(n*HEADS + h)*HW_*HDD + quarter*8;

            #pragma unroll
            for (int p = 0; p < 8; ++p) {
                const int z = p & 3;
                const float wp = s_att[ql][h*8+p];   // precomputed probability
                const float ax = s_ref[ql][z*2+0]*WF_ + s_off[ql][h*16+p*2+0] - 0.5f;
                const float ay = s_ref[ql][z*2+1]*HF_ + s_off[ql][h*16+p*2+1] - 0.5f;
                const float fx = floorf(ax), fy = floorf(ay);
                const float dx = ax-fx, dy = ay-fy;
                const int x0 = (int)fx, y0 = (int)fy;
                #pragma unroll
                for (int oy = 0; oy < 2; ++oy) {
                    const int yi = y0 + oy;
                    const float wy = oy ? dy : 1.f-dy;
                    #pragma unroll
                    for (int ox = 0; ox < 2; ++ox) {
                        const int xi = x0 + ox;
                        const float wx = ox ? dx : 1.f-dx;
                        const bool valid = ((unsigned)xi < WF_) & ((unsigned)yi < HF_);
                        const float cw = valid ? wp*wy*wx : 0.f;
                        const int xc = min(max(xi, 0), WF_-1);
                        const int yc = min(max(yi, 0), HF_-1);
                        const ushort8_t v = *(const ushort8_t*)(vbase + (size_t)(yc*WF_ + xc)*HDD);
                        #pragma unroll
                        for (int c = 0; c < 8; ++c)
                            acc[c] += cw * __uint_as_float(((unsigned)v[c]) << 16);
                    }
                }
            }
        }
    }

    const float sc = s_scl[ql];
    ushort8_t o;
    #pragma unroll
    for (int c = 0; c < 8; ++c) o[c] = f2bf(acc[c]*sc);
    *(ushort8_t*)(asum_bf + ((size_t)(q0+ql))*DIM + h*HDD + quarter*8) = o;
}

// ---------------------------------------------------------------------------
// K_tail: FUSED inner+output projection (unchanged).
// ---------------------------------------------------------------------------
__global__ __launch_bounds__(256)
void k_tail(const unsigned short* __restrict__ asum_bf,
            const unsigned short* __restrict__ Wi_bf,
            const unsigned short* __restrict__ Wz_bf,
            const float* __restrict__ bi, const float* __restrict__ bz,
            const float* __restrict__ biasf, float* __restrict__ out)
{
    __shared__ char smraw[32*260*4];   // union: S_lds bf16[32][264] / C_lds f32[32][260]
    unsigned short (*S_lds)[264] = (unsigned short (*)[264])smraw;
    float (*C_lds)[260] = (float (*)[260])smraw;

    const int m0 = blockIdx.x * 32;
    const int tid = threadIdx.x;
    const int lane = tid & 63, wave = tid >> 6;
    const int quad = lane >> 4, l15 = lane & 15;
    const int n0 = wave * 64;

    const int r0 = m0 + l15;
    const int r1 = m0 + 16 + l15;
    const unsigned short* a0p = asum_bf + (size_t)(r0 < NQ ? r0 : 0)*DIM;
    const unsigned short* a1p = asum_bf + (size_t)(r1 < NQ ? r1 : 0)*DIM;

    // --- phase 1: S = asum · Wi^T ---
    f32x4 acc[2][4] = {};
    #pragma unroll
    for (int kc = 0; kc < 8; ++kc) {
        const int kk = kc*32 + quad*8;
        const bf16x8 a0 = *(const bf16x8*)(a0p + kk);
        const bf16x8 a1 = *(const bf16x8*)(a1p + kk);
        #pragma unroll
        for (int nt = 0; nt < 4; ++nt) {
            const bf16x8 b = *(const bf16x8*)(Wi_bf + (size_t)(n0 + nt*16 + l15)*DIM + kk);
            acc[0][nt] = __builtin_amdgcn_mfma_f32_16x16x32_bf16(a0, b, acc[0][nt], 0,0,0);
            acc[1][nt] = __builtin_amdgcn_mfma_f32_16x16x32_bf16(a1, b, acc[1][nt], 0,0,0);
        }
    }
    #pragma unroll
    for (int nt = 0; nt < 4; ++nt) {
        const int col = n0 + nt*16 + l15;
        const float bj = bi[col];
        #pragma unroll
        for (int mt = 0; mt < 2; ++mt) {
            #pragma unroll
            for (int r = 0; r < 4; ++r) {
                const int m = m0 + mt*16 + quad*4 + r;
                const float f = (m < NQ) ? biasf[m] : 0.f;
                S_lds[mt*16 + quad*4 + r][col] = f2bf(acc[mt][nt][r] + f*bj);
            }
        }
    }
    __syncthreads();

    // --- phase 2: out = S · Wz^T ---
    f32x4 acc2[2][4] = {};
    #pragma unroll
    for (int kc = 0; kc < 8; ++kc) {
        const int kk = kc*32 + quad*8;
        const bf16x8 s0 = *(const bf16x8*)&S_lds[l15][kk];
        const bf16x8 s1 = *(const bf16x8*)&S_lds[16 + l15][kk];
        #pragma unroll
        for (int nt = 0; nt < 4; ++nt) {
            const bf16x8 b = *(const bf16x8*)(Wz_bf + (size_t)(n0 + nt*16 + l15)*DIM + kk);
            acc2[0][nt] = __builtin_amdgcn_mfma_f32_16x16x32_bf16(s0, b, acc2[0][nt], 0,0,0);
            acc2[1][nt] = __builtin_amdgcn_mfma_f32_16x16x32_bf16(s1, b, acc2[1][nt], 0,0,0);
        }
    }
    __syncthreads();   // all S_lds reads done before C_lds overwrite
    #pragma unroll
    for (int nt = 0; nt < 4; ++nt) {
        const int col = n0 + nt*16 + l15;
        const float bj = bz[col];
        #pragma unroll
        for (int mt = 0; mt < 2; ++mt) {
            #pragma unroll
            for (int r = 0; r < 4; ++r)
                C_lds[mt*16 + quad*4 + r][col] = acc2[mt][nt][r] + bj;
        }
    }
    __syncthreads();
    // coalesced stores: 32 rows x 256 f32 = 2048 float4, 8/thread
    #pragma unroll
    for (int i = 0; i < 8; ++i) {
        const int idx = i*256 + tid;
        const int row = idx >> 6, c4 = (idx & 63)*4;
        const int m = m0 + row;
        if (m < NQ)
            *(float4*)(out + (size_t)m*DIM + c4) = *(float4*)&C_lds[row][c4];
    }
}

// ---------------------------------------------------------------------------
extern "C" void kernel_launch(void* const* d_in, const int* in_sizes, int n_in,
                              void* d_out, int out_size, void* d_ws, size_t ws_size,
                              hipStream_t stream)
{
    const float* queries = (const float*)d_in[0];
    const float* pos_emb = (const float*)d_in[1];
    const float* lvl_emb = (const float*)d_in[2];
    const float* cam_emb = (const float*)d_in[3];
    const float* features= (const float*)d_in[4];
    const float* ref3d   = (const float*)d_in[5];
    const int*   bev     = (const int*)d_in[6];
    const float* Wv = (const float*)d_in[7];
    const float* bv = (const float*)d_in[8];
    const float* Wo = (const float*)d_in[9];
    const float* bo = (const float*)d_in[10];
    const float* Wa = (const float*)d_in[11];
    const float* ba = (const float*)d_in[12];
    const float* Wi = (const float*)d_in[13];
    const float* bi = (const float*)d_in[14];
    const float* Wz = (const float*)d_in[15];
    const float* bz = (const float*)d_in[16];
    float* out = (float*)d_out;

    char* ws = (char*)d_ws;
    size_t o = 0;
    auto alloc = [&](size_t bytes) { char* p = ws + o; o += (bytes + 255) & ~size_t(255); return p; };
    unsigned short* value_bf = (unsigned short*)alloc((size_t)BN*HEADS*HW_*HDD*2);  // 8.65 MB
    float* off_ws   = (float*)alloc((size_t)MTOT*128*4);                            // 30.7 MB
    float* attw_ws  = (float*)alloc((size_t)MTOT*64*4);                             // 15.4 MB
    unsigned short* asum_bf  = (unsigned short*)alloc((size_t)NQ*DIM*2);            // 5.1 MB
    unsigned short* Wv_bf  = (unsigned short*)alloc(65536*2);
    unsigned short* Woa_bf = (unsigned short*)alloc(49152*2);
    unsigned short* Wi_bf  = (unsigned short*)alloc(65536*2);
    unsigned short* Wz_bf  = (unsigned short*)alloc(65536*2);
    float* hitf   = (float*)alloc((size_t)BN*NQ*4);
    float* scalev = (float*)alloc(NQ*4);
    float* biasf  = (float*)alloc(NQ*4);
    float* ebias  = (float*)alloc(BN*DIM*4);
    // total ~61 MB

    k_prep  <<<128, 256, 0, stream>>>(Wv, Wo, Wa, Wi, Wz, lvl_emb, cam_emb, bv, bev,
                                      Wv_bf, Woa_bf, Wi_bf, Wz_bf,
                                      ebias, hitf, scalev, biasf);
    k_value_mfma<<<dim3(HW_/16, 1, BN), 256, 0, stream>>>(features, Wv_bf, ebias, value_bf);
    k_offattn<<<MTOT/32, 256, 0, stream>>>(queries, pos_emb, Woa_bf, bo, ba, off_ws, attw_ws);
    k_sample <<<NQ/8, 256, 0, stream>>>(value_bf, off_ws, attw_ws, ref3d, hitf, scalev, asum_bf);
    k_tail   <<<(NQ+31)/32, 256, 0, stream>>>(asum_bf, Wi_bf, Wz_bf, bi, bz, biasf, out);
}